// Round 3
// baseline (209.545 us; speedup 1.0000x reference)
//
#include <hip/hip_runtime.h>

// Shapes: msa [1,128,256,256] f32, pair [1,256,256,128] f32, out same as pair.
// ws: leftT [256 l][4 kk][2 iLow][64 lane][8] bf16  (MFMA A-fragment-direct)
//     rightT same | w3 [16 ck][2 inner][8 w][64 lane][8 e] bf16 (B-fragment-direct)
//     | wTg [64 c][256 d] bf16

typedef float v4f __attribute__((ext_vector_type(4)));
typedef short v8s __attribute__((ext_vector_type(8)));

static __device__ inline unsigned short f2bf(float x) {
    unsigned int u = __builtin_bit_cast(unsigned int, x);
    return (unsigned short)((u + 0x7fffu + ((u >> 16) & 1u)) >> 16);
}

// ---------------- one-time weight reformat ----------------
// blocks 0..63: w3 (fragment-direct layout, p = w*16+l15); blocks 64..71: wTg [c][d]
__global__ __launch_bounds__(256) void k_prep(const float* __restrict__ w_out,
                                              const float* __restrict__ wl,
                                              const float* __restrict__ wr,
                                              unsigned short* __restrict__ w3,
                                              unsigned short* __restrict__ wTg) {
    const int b = blockIdx.x, t = threadIdx.x;
    unsigned short tmp[8];
    if (b < 64) {
        int tgt = b * 2048 + t * 8;            // linear in w3
        int lane6 = (tgt >> 3) & 63, quad = lane6 >> 4, l15 = lane6 & 15;
        int w = (tgt >> 9) & 7;                // 8 waves
        int inner = (tgt >> 12) & 1, ck = tgt >> 13;
        int p = w * 16 + l15;
        for (int e = 0; e < 8; ++e) {
            int kp = ck * 64 + inner * 32 + quad * 8 + e;   // k' this lane-element feeds
            int j1 = (kp >> 9) & 1, qd = (kp >> 7) & 3, lp = (kp >> 3) & 15;
            int i1 = (kp >> 2) & 1, r = kp & 3;
            int ii = i1 * 16 + qd * 4 + r, jj = j1 * 16 + lp;
            tmp[e] = f2bf(w_out[(ii * 32 + jj) * 128 + p]);
        }
        *(uint4*)&w3[tgt] = *(const uint4*)tmp;
    } else {
        int tgt = (b - 64) * 2048 + t * 8;     // linear = c*256 + d
        int c = tgt >> 8, d0 = tgt & 255;
        const float* src = (c < 32) ? wl : wr;
        int cc = c & 31;
        for (int e = 0; e < 8; ++e) tmp[e] = f2bf(src[(d0 + e) * 32 + cc]);
        *(uint4*)&wTg[tgt] = *(const uint4*)tmp;
    }
}

// ---------------- LayerNorm + left/right projection ----------------
// grid (256 l, 4 s-quarters), block 256.
__global__ __launch_bounds__(256) void k_lnproj(
    const float* __restrict__ msa, const float* __restrict__ gamma, const float* __restrict__ beta,
    const unsigned short* __restrict__ wTg, const float* __restrict__ bl, const float* __restrict__ br,
    unsigned short* __restrict__ leftT, unsigned short* __restrict__ rightT) {
    __shared__ unsigned short xb[32 * 264];     // [32 s][256 d + 8 pad]
    __shared__ unsigned short wlds[64 * 264];   // [64 c][256 d + 8 pad]
    __shared__ unsigned short outT[64 * 40];    // [64 c][32 s + 8 pad]

    const int t = threadIdx.x, lane = t & 63, w = t >> 6;
    const int l = blockIdx.x, s0 = blockIdx.y * 32;
    const int quad = lane >> 4, l15 = lane & 15;

    // stage W: coalesced b128, padded rows (min-conflict writes)
    for (int it = 0; it < 8; ++it) {
        int idx = it * 2048 + t * 8;
        *(uint4*)&wlds[(idx >> 8) * 264 + (idx & 255)] = *(const uint4*)&wTg[idx];
    }

    // LayerNorm: wave does 8 rows, reduction batched for 8-way ILP
    float4 g4 = *(const float4*)&gamma[lane * 4];
    float4 be4 = *(const float4*)&beta[lane * 4];
    float4 vr[8]; float s1[8], s2[8];
    for (int r = 0; r < 8; ++r) {
        const float* row = msa + (size_t)((s0 + w * 8 + r) * 256 + l) * 256;
        vr[r] = *(const float4*)&row[lane * 4];
    }
    for (int r = 0; r < 8; ++r) {
        float4 v = vr[r];
        s1[r] = v.x + v.y + v.z + v.w;
        s2[r] = v.x * v.x + v.y * v.y + v.z * v.z + v.w * v.w;
    }
    for (int o = 32; o > 0; o >>= 1)
        for (int r = 0; r < 8; ++r) { s1[r] += __shfl_xor(s1[r], o); s2[r] += __shfl_xor(s2[r], o); }
    for (int r = 0; r < 8; ++r) {
        float mu = s1[r] * (1.f / 256);
        float rs = rsqrtf(s2[r] * (1.f / 256) - mu * mu + 1e-5f);
        float4 v = vr[r];
        ushort4 xs;
        xs.x = f2bf((v.x - mu) * rs * g4.x + be4.x);
        xs.y = f2bf((v.y - mu) * rs * g4.y + be4.y);
        xs.z = f2bf((v.z - mu) * rs * g4.z + be4.z);
        xs.w = f2bf((v.w - mu) * rs * g4.w + be4.w);
        *(ushort4*)&xb[(w * 8 + r) * 264 + lane * 4] = xs;
    }
    __syncthreads();

    // MFMA: M=32 (s), N=64 (c), K=256
    const int mt = w >> 1, ntb = (w & 1) * 2;
    v4f acc[2] = {};
    const int frow = (mt * 16 + l15) * 264;
    for (int ks = 0; ks < 8; ++ks) {
        int k = ks * 32 + quad * 8;
        v8s a = *(const v8s*)&xb[frow + k];
        v8s b0 = *(const v8s*)&wlds[(ntb * 16 + l15) * 264 + k];
        v8s b1 = *(const v8s*)&wlds[((ntb + 1) * 16 + l15) * 264 + k];
        acc[0] = __builtin_amdgcn_mfma_f32_16x16x32_bf16(a, b0, acc[0], 0, 0, 0);
        acc[1] = __builtin_amdgcn_mfma_f32_16x16x32_bf16(a, b1, acc[1], 0, 0, 0);
    }

    for (int tn = 0; tn < 2; ++tn) {
        int c = (ntb + tn) * 16 + l15;
        float bias = c < 32 ? bl[c] : br[c - 32];
        float scale = c < 32 ? 1.f : (1.f / 128);
        for (int r = 0; r < 4; ++r)
            outT[c * 40 + mt * 16 + quad * 4 + r] = f2bf((acc[tn][r] + bias) * scale);
    }
    __syncthreads();

    // fragment-direct global writes: element (c, s = by*32 + sl) ->
    //   T[l*4096 + by*1024 + (c>>4)*512 + (sl>>3)*128 + (c&15)*8 + (sl&7)]
    {
        int c = t >> 2, q = t & 3;               // q = sl chunk (8 s each)
        uint4 vv = *(const uint4*)&outT[c * 40 + q * 8];
        int cc = c & 31;
        unsigned short* base = (c < 32) ? leftT : rightT;
        unsigned short* dst = base + l * 4096 + blockIdx.y * 1024
                            + (cc >> 4) * 512 + q * 128 + (cc & 15) * 8;
        *(uint4*)dst = vv;
    }
}

// ---------------- fused outer-product + w_out projection ----------------
// grid (32,64): 8x4 (l,m) tile = 32 pixels, 512 threads (8 waves, 4x2 phase A).
// Phase B: each wave owns a distinct 16-wide p-slice -> w3 read ONCE per block.
__global__ __launch_bounds__(512, 4) void k_outer(
    const unsigned short* __restrict__ leftT, const unsigned short* __restrict__ rightT,
    const unsigned short* __restrict__ w2g, const float* __restrict__ bout,
    const float* __restrict__ pairIn, float* __restrict__ out) {
    __shared__ alignas(16) unsigned short Obuf[32768];   // [32 pix][1024 k'], XOR-swizzled

    const int t = threadIdx.x, lane = t & 63, w = t >> 6;
    const int l0 = blockIdx.x * 8, m0 = blockIdx.y * 4;
    const int wm = w & 3, wn = w >> 2;
    const int quad = lane >> 4, l15 = lane & 15;

    // ---- issue-early: first w3 fragments + pairIn (hide L2/HBM latency)
    const unsigned short* wsrc = w2g + w * 512 + lane * 8;
    v8s f0 = *(const v8s*)&wsrc[0];        // (ck=0, inner=0)
    v8s f1 = *(const v8s*)&wsrc[4096];     // (ck=0, inner=1)
    const int p = w * 16 + l15;
    float pfv[8];
#pragma unroll
    for (int pm = 0; pm < 2; ++pm)
#pragma unroll
        for (int r = 0; r < 4; ++r) {
            int P = pm * 16 + quad * 4 + r;
            size_t idx = (size_t)((l0 + (P >> 2)) * 256 + (m0 + (P & 3))) * 128 + p;
            pfv[pm * 4 + r] = pairIn[idx];
        }

    const unsigned short* Asrc = leftT + l0 * 4096;
    const unsigned short* Bsrc = rightT + m0 * 4096;

    // ---- phase A: C[256 x 128] = A·B^T over K=s=128, fragment-direct from L2.
    //      Wave (wm,wn) owns a 64x64 strip: 4x4 accs. No LDS, no barriers.
    v4f acc[4][4] = {};
#pragma unroll
    for (int kk = 0; kk < 4; ++kk) {
        v8s a[4], bb[4];
#pragma unroll
        for (int i = 0; i < 4; ++i)
            a[i] = *(const v8s*)&Asrc[(wm * 2 + (i >> 1)) * 4096 + kk * 1024 + (i & 1) * 512 + lane * 8];
#pragma unroll
        for (int j = 0; j < 4; ++j)
            bb[j] = *(const v8s*)&Bsrc[(wn * 2 + (j >> 1)) * 4096 + kk * 1024 + (j & 1) * 512 + lane * 8];
#pragma unroll
        for (int i = 0; i < 4; ++i)
#pragma unroll
            for (int j = 0; j < 4; ++j)
                acc[i][j] = __builtin_amdgcn_mfma_f32_16x16x32_bf16(a[i], bb[j], acc[i][j], 0, 0, 0);
    }

    // ---- scatter acc -> Obuf. Pixel P = l_local*4 + m_local; per (P, j1) the lane
    //      writes 8 consecutive k' = j1*512 + quad*128 + l15*8 + i1*4 + r.
    for (int a2 = 0; a2 < 2; ++a2)
        for (int b2 = 0; b2 < 2; ++b2) {
            int P = (wm * 2 + a2) * 4 + wn * 2 + b2;
            for (int j1 = 0; j1 < 2; ++j1) {
                unsigned short tmp8[8];
                for (int i1 = 0; i1 < 2; ++i1)
                    for (int r = 0; r < 4; ++r)
                        tmp8[i1 * 4 + r] = f2bf(acc[a2 * 2 + i1][b2 * 2 + j1][r]);
                int pg = (j1 * 64 + lane) ^ (P & 7) ^ ((P & 8) << 3);
                *(uint4*)&Obuf[P * 1024 + pg * 8] = *(const uint4*)tmp8;
            }
        }
    __syncthreads();

    // ---- phase B: P[32][128] = Obuf @ W2. Wave's p-slice = [w*16, w*16+16).
    //      Per ck: 2 w3 loads (prefetched 1 ahead) + 4 Obuf reads + 4 MFMA.
    v4f acc2[2] = {};
#pragma unroll
    for (int ck = 0; ck < 16; ++ck) {
        v8s c0 = f0, c1 = f1;
        if (ck < 15) {
            const unsigned short* nx = wsrc + (ck + 1) * 8192;
            f0 = *(const v8s*)&nx[0];
            f1 = *(const v8s*)&nx[4096];
        }
        {
            int g = ck * 8 + quad;
            int ch = ((g ^ (l15 & 7) ^ ((l15 & 8) << 3)) << 3);
            v8s a0 = *(const v8s*)&Obuf[l15 * 1024 + ch];
            v8s a1 = *(const v8s*)&Obuf[(16 + l15) * 1024 + ch];
            acc2[0] = __builtin_amdgcn_mfma_f32_16x16x32_bf16(a0, c0, acc2[0], 0, 0, 0);
            acc2[1] = __builtin_amdgcn_mfma_f32_16x16x32_bf16(a1, c0, acc2[1], 0, 0, 0);
        }
        {
            int g = ck * 8 + 4 + quad;
            int ch = ((g ^ (l15 & 7) ^ ((l15 & 8) << 3)) << 3);
            v8s a0 = *(const v8s*)&Obuf[l15 * 1024 + ch];
            v8s a1 = *(const v8s*)&Obuf[(16 + l15) * 1024 + ch];
            acc2[0] = __builtin_amdgcn_mfma_f32_16x16x32_bf16(a0, c1, acc2[0], 0, 0, 0);
            acc2[1] = __builtin_amdgcn_mfma_f32_16x16x32_bf16(a1, c1, acc2[1], 0, 0, 0);
        }
    }

    // ---- epilogue: out = pair + P + b_out
    float bo = bout[p];
#pragma unroll
    for (int pm = 0; pm < 2; ++pm)
#pragma unroll
        for (int r = 0; r < 4; ++r) {
            int P = pm * 16 + quad * 4 + r;
            size_t idx = (size_t)((l0 + (P >> 2)) * 256 + (m0 + (P & 3))) * 128 + p;
            out[idx] = pfv[pm * 4 + r] + bo + acc2[pm][r];
        }
}

extern "C" void kernel_launch(void* const* d_in, const int* in_sizes, int n_in,
                              void* d_out, int out_size, void* d_ws, size_t ws_size,
                              hipStream_t stream) {
    const float* msa   = (const float*)d_in[0];
    const float* pairI = (const float*)d_in[1];
    const float* gamma = (const float*)d_in[4];
    const float* beta  = (const float*)d_in[5];
    const float* wl    = (const float*)d_in[6];
    const float* bl    = (const float*)d_in[7];
    const float* wr    = (const float*)d_in[8];
    const float* br    = (const float*)d_in[9];
    const float* wout  = (const float*)d_in[10];
    const float* bout  = (const float*)d_in[11];
    float* out = (float*)d_out;

    unsigned short* leftT  = (unsigned short*)d_ws;
    unsigned short* rightT = leftT + 256 * 32 * 128;
    unsigned short* w3     = rightT + 256 * 32 * 128;
    unsigned short* wTg    = w3 + 131072;

    k_prep<<<dim3(72), 256, 0, stream>>>(wout, wl, wr, w3, wTg);
    k_lnproj<<<dim3(256, 4), 256, 0, stream>>>(msa, gamma, beta, wTg, bl, br, leftT, rightT);
    k_outer<<<dim3(32, 64), 512, 0, stream>>>(leftT, rightT, w3, bout, pairI, out);
}

// Round 4
// 190.103 us; speedup vs baseline: 1.1023x; 1.1023x over previous
//
#include <hip/hip_runtime.h>

// Shapes: msa [1,128,256,256] f32, pair [1,256,256,128] f32, out same as pair.
// ws: leftT [256 l][4 kk][2 iLow][64 lane][8] bf16  (MFMA A-fragment-direct)
//     rightT same | w3 [16 ck][2 inner][8 w][64 lane][8 e] bf16 (B-fragment-direct)
//     | wTg [64 c][256 d] bf16

typedef float v4f __attribute__((ext_vector_type(4)));
typedef short v8s __attribute__((ext_vector_type(8)));

static __device__ inline unsigned short f2bf(float x) {
    unsigned int u = __builtin_bit_cast(unsigned int, x);
    return (unsigned short)((u + 0x7fffu + ((u >> 16) & 1u)) >> 16);
}

// ---------------- one-time weight reformat ----------------
// blocks 0..63: w3 (fragment-direct layout, p = w*16+l15); blocks 64..71: wTg [c][d]
__global__ __launch_bounds__(256) void k_prep(const float* __restrict__ w_out,
                                              const float* __restrict__ wl,
                                              const float* __restrict__ wr,
                                              unsigned short* __restrict__ w3,
                                              unsigned short* __restrict__ wTg) {
    const int b = blockIdx.x, t = threadIdx.x;
    unsigned short tmp[8];
    if (b < 64) {
        int tgt = b * 2048 + t * 8;            // linear in w3
        int lane6 = (tgt >> 3) & 63, quad = lane6 >> 4, l15 = lane6 & 15;
        int w = (tgt >> 9) & 7;                // 8 waves
        int inner = (tgt >> 12) & 1, ck = tgt >> 13;
        int p = w * 16 + l15;
        for (int e = 0; e < 8; ++e) {
            int kp = ck * 64 + inner * 32 + quad * 8 + e;   // k' this lane-element feeds
            int j1 = (kp >> 9) & 1, qd = (kp >> 7) & 3, lp = (kp >> 3) & 15;
            int i1 = (kp >> 2) & 1, r = kp & 3;
            int ii = i1 * 16 + qd * 4 + r, jj = j1 * 16 + lp;
            tmp[e] = f2bf(w_out[(ii * 32 + jj) * 128 + p]);
        }
        *(uint4*)&w3[tgt] = *(const uint4*)tmp;
    } else {
        int tgt = (b - 64) * 2048 + t * 8;     // linear = c*256 + d
        int c = tgt >> 8, d0 = tgt & 255;
        const float* src = (c < 32) ? wl : wr;
        int cc = c & 31;
        for (int e = 0; e < 8; ++e) tmp[e] = f2bf(src[(d0 + e) * 32 + cc]);
        *(uint4*)&wTg[tgt] = *(const uint4*)tmp;
    }
}

// ---------------- LayerNorm + left/right projection ----------------
// grid (256 l, 4 s-quarters), block 256.
__global__ __launch_bounds__(256) void k_lnproj(
    const float* __restrict__ msa, const float* __restrict__ gamma, const float* __restrict__ beta,
    const unsigned short* __restrict__ wTg, const float* __restrict__ bl, const float* __restrict__ br,
    unsigned short* __restrict__ leftT, unsigned short* __restrict__ rightT) {
    __shared__ unsigned short xb[32 * 264];     // [32 s][256 d + 8 pad]
    __shared__ unsigned short wlds[64 * 264];   // [64 c][256 d + 8 pad]
    __shared__ unsigned short outT[64 * 40];    // [64 c][32 s + 8 pad]

    const int t = threadIdx.x, lane = t & 63, w = t >> 6;
    const int l = blockIdx.x, s0 = blockIdx.y * 32;
    const int quad = lane >> 4, l15 = lane & 15;

    // stage W: coalesced b128, padded rows (min-conflict writes)
    for (int it = 0; it < 8; ++it) {
        int idx = it * 2048 + t * 8;
        *(uint4*)&wlds[(idx >> 8) * 264 + (idx & 255)] = *(const uint4*)&wTg[idx];
    }

    // LayerNorm: wave does 8 rows, reduction batched for 8-way ILP
    float4 g4 = *(const float4*)&gamma[lane * 4];
    float4 be4 = *(const float4*)&beta[lane * 4];
    float4 vr[8]; float s1[8], s2[8];
    for (int r = 0; r < 8; ++r) {
        const float* row = msa + (size_t)((s0 + w * 8 + r) * 256 + l) * 256;
        vr[r] = *(const float4*)&row[lane * 4];
    }
    for (int r = 0; r < 8; ++r) {
        float4 v = vr[r];
        s1[r] = v.x + v.y + v.z + v.w;
        s2[r] = v.x * v.x + v.y * v.y + v.z * v.z + v.w * v.w;
    }
    for (int o = 32; o > 0; o >>= 1)
        for (int r = 0; r < 8; ++r) { s1[r] += __shfl_xor(s1[r], o); s2[r] += __shfl_xor(s2[r], o); }
    for (int r = 0; r < 8; ++r) {
        float mu = s1[r] * (1.f / 256);
        float rs = rsqrtf(s2[r] * (1.f / 256) - mu * mu + 1e-5f);
        float4 v = vr[r];
        ushort4 xs;
        xs.x = f2bf((v.x - mu) * rs * g4.x + be4.x);
        xs.y = f2bf((v.y - mu) * rs * g4.y + be4.y);
        xs.z = f2bf((v.z - mu) * rs * g4.z + be4.z);
        xs.w = f2bf((v.w - mu) * rs * g4.w + be4.w);
        *(ushort4*)&xb[(w * 8 + r) * 264 + lane * 4] = xs;
    }
    __syncthreads();

    // MFMA: M=32 (s), N=64 (c), K=256
    const int mt = w >> 1, ntb = (w & 1) * 2;
    v4f acc[2] = {};
    const int frow = (mt * 16 + l15) * 264;
    for (int ks = 0; ks < 8; ++ks) {
        int k = ks * 32 + quad * 8;
        v8s a = *(const v8s*)&xb[frow + k];
        v8s b0 = *(const v8s*)&wlds[(ntb * 16 + l15) * 264 + k];
        v8s b1 = *(const v8s*)&wlds[((ntb + 1) * 16 + l15) * 264 + k];
        acc[0] = __builtin_amdgcn_mfma_f32_16x16x32_bf16(a, b0, acc[0], 0, 0, 0);
        acc[1] = __builtin_amdgcn_mfma_f32_16x16x32_bf16(a, b1, acc[1], 0, 0, 0);
    }

    for (int tn = 0; tn < 2; ++tn) {
        int c = (ntb + tn) * 16 + l15;
        float bias = c < 32 ? bl[c] : br[c - 32];
        float scale = c < 32 ? 1.f : (1.f / 128);
        for (int r = 0; r < 4; ++r)
            outT[c * 40 + mt * 16 + quad * 4 + r] = f2bf((acc[tn][r] + bias) * scale);
    }
    __syncthreads();

    // fragment-direct global writes: element (c, s = by*32 + sl) ->
    //   T[l*4096 + by*1024 + (c>>4)*512 + (sl>>3)*128 + (c&15)*8 + (sl&7)]
    {
        int c = t >> 2, q = t & 3;               // q = sl chunk (8 s each)
        uint4 vv = *(const uint4*)&outT[c * 40 + q * 8];
        int cc = c & 31;
        unsigned short* base = (c < 32) ? leftT : rightT;
        unsigned short* dst = base + l * 4096 + blockIdx.y * 1024
                            + (cc >> 4) * 512 + q * 128 + (cc & 15) * 8;
        *(uint4*)dst = vv;
    }
}

// ---------------- fused outer-product + w_out projection ----------------
// grid (32,64): 8x4 (l,m) tile = 32 pixels, 512 threads (8 waves, 4x2 phase A).
// Phase B: each wave owns a distinct 16-wide p-slice -> w3 read ONCE per block.
// Epilogue: LDS transpose (Pbuf) -> full-512B-row coalesced pair/out traffic.
__global__ __launch_bounds__(512, 4) void k_outer(
    const unsigned short* __restrict__ leftT, const unsigned short* __restrict__ rightT,
    const unsigned short* __restrict__ w2g, const float* __restrict__ bout,
    const float* __restrict__ pairIn, float* __restrict__ out) {
    __shared__ alignas(16) unsigned short Obuf[32768];   // [32 pix][1024 k'], XOR-swizzled
    float* Pbuf = (float*)Obuf;                          // aliased [32 pix][132] f32 (17 KB)

    const int t = threadIdx.x, lane = t & 63, w = t >> 6;
    const int l0 = blockIdx.x * 8, m0 = blockIdx.y * 4;
    const int wm = w & 3, wn = w >> 2;
    const int quad = lane >> 4, l15 = lane & 15;

    // ---- issue-early: first w3 fragments + pairIn rows (full-line pattern)
    const unsigned short* wsrc = w2g + w * 512 + lane * 8;
    v8s f0 = *(const v8s*)&wsrc[0];        // (ck=0, inner=0)
    v8s f1 = *(const v8s*)&wsrc[4096];     // (ck=0, inner=1)
    float2 pf2[4];
    size_t oidx[4];
#pragma unroll
    for (int sub = 0; sub < 4; ++sub) {
        int P = w * 4 + sub;               // wave owns 4 full pixel rows
        oidx[sub] = (size_t)((l0 + (P >> 2)) * 256 + (m0 + (P & 3))) * 128 + lane * 2;
        pf2[sub] = *(const float2*)&pairIn[oidx[sub]];
    }

    const unsigned short* Asrc = leftT + l0 * 4096;
    const unsigned short* Bsrc = rightT + m0 * 4096;

    // ---- phase A: C[256 x 128] = A·B^T over K=s=128, fragment-direct from L2.
    //      Wave (wm,wn) owns a 64x64 strip: 4x4 accs. No LDS, no barriers.
    v4f acc[4][4] = {};
#pragma unroll
    for (int kk = 0; kk < 4; ++kk) {
        v8s a[4], bb[4];
#pragma unroll
        for (int i = 0; i < 4; ++i)
            a[i] = *(const v8s*)&Asrc[(wm * 2 + (i >> 1)) * 4096 + kk * 1024 + (i & 1) * 512 + lane * 8];
#pragma unroll
        for (int j = 0; j < 4; ++j)
            bb[j] = *(const v8s*)&Bsrc[(wn * 2 + (j >> 1)) * 4096 + kk * 1024 + (j & 1) * 512 + lane * 8];
#pragma unroll
        for (int i = 0; i < 4; ++i)
#pragma unroll
            for (int j = 0; j < 4; ++j)
                acc[i][j] = __builtin_amdgcn_mfma_f32_16x16x32_bf16(a[i], bb[j], acc[i][j], 0, 0, 0);
    }

    // ---- scatter acc -> Obuf. Pixel P = l_local*4 + m_local; per (P, j1) the lane
    //      writes 8 consecutive k' = j1*512 + quad*128 + l15*8 + i1*4 + r.
    for (int a2 = 0; a2 < 2; ++a2)
        for (int b2 = 0; b2 < 2; ++b2) {
            int P = (wm * 2 + a2) * 4 + wn * 2 + b2;
            for (int j1 = 0; j1 < 2; ++j1) {
                unsigned short tmp8[8];
                for (int i1 = 0; i1 < 2; ++i1)
                    for (int r = 0; r < 4; ++r)
                        tmp8[i1 * 4 + r] = f2bf(acc[a2 * 2 + i1][b2 * 2 + j1][r]);
                int pg = (j1 * 64 + lane) ^ (P & 7) ^ ((P & 8) << 3);
                *(uint4*)&Obuf[P * 1024 + pg * 8] = *(const uint4*)tmp8;
            }
        }
    __syncthreads();

    // ---- phase B: P[32][128] = Obuf @ W2. Wave's p-slice = [w*16, w*16+16).
    //      Per ck: 2 w3 loads (prefetched 1 ahead) + 4 Obuf reads + 4 MFMA.
    const int p = w * 16 + l15;
    v4f acc2[2] = {};
#pragma unroll
    for (int ck = 0; ck < 16; ++ck) {
        v8s c0 = f0, c1 = f1;
        if (ck < 15) {
            const unsigned short* nx = wsrc + (ck + 1) * 8192;
            f0 = *(const v8s*)&nx[0];
            f1 = *(const v8s*)&nx[4096];
        }
        {
            int g = ck * 8 + quad;
            int ch = ((g ^ (l15 & 7) ^ ((l15 & 8) << 3)) << 3);
            v8s a0 = *(const v8s*)&Obuf[l15 * 1024 + ch];
            v8s a1 = *(const v8s*)&Obuf[(16 + l15) * 1024 + ch];
            acc2[0] = __builtin_amdgcn_mfma_f32_16x16x32_bf16(a0, c0, acc2[0], 0, 0, 0);
            acc2[1] = __builtin_amdgcn_mfma_f32_16x16x32_bf16(a1, c0, acc2[1], 0, 0, 0);
        }
        {
            int g = ck * 8 + 4 + quad;
            int ch = ((g ^ (l15 & 7) ^ ((l15 & 8) << 3)) << 3);
            v8s a0 = *(const v8s*)&Obuf[l15 * 1024 + ch];
            v8s a1 = *(const v8s*)&Obuf[(16 + l15) * 1024 + ch];
            acc2[0] = __builtin_amdgcn_mfma_f32_16x16x32_bf16(a0, c1, acc2[0], 0, 0, 0);
            acc2[1] = __builtin_amdgcn_mfma_f32_16x16x32_bf16(a1, c1, acc2[1], 0, 0, 0);
        }
    }
    __syncthreads();   // all Obuf reads done before Pbuf overwrite

    // ---- transpose through LDS: Pbuf[P][p] = acc2 + bias (2-way conflict = free)
    {
        float bo = bout[p];
#pragma unroll
        for (int pm = 0; pm < 2; ++pm)
#pragma unroll
            for (int r = 0; r < 4; ++r) {
                int P = pm * 16 + quad * 4 + r;
                Pbuf[P * 132 + p] = acc2[pm][r] + bo;
            }
    }
    __syncthreads();

    // ---- epilogue: full-line coalesced out = pair + P (512 B per wave-instr)
#pragma unroll
    for (int sub = 0; sub < 4; ++sub) {
        int P = w * 4 + sub;
        float2 ov;
        ov.x = pf2[sub].x + Pbuf[P * 132 + lane * 2];
        ov.y = pf2[sub].y + Pbuf[P * 132 + lane * 2 + 1];
        *(float2*)&out[oidx[sub]] = ov;
    }
}

extern "C" void kernel_launch(void* const* d_in, const int* in_sizes, int n_in,
                              void* d_out, int out_size, void* d_ws, size_t ws_size,
                              hipStream_t stream) {
    const float* msa   = (const float*)d_in[0];
    const float* pairI = (const float*)d_in[1];
    const float* gamma = (const float*)d_in[4];
    const float* beta  = (const float*)d_in[5];
    const float* wl    = (const float*)d_in[6];
    const float* bl    = (const float*)d_in[7];
    const float* wr    = (const float*)d_in[8];
    const float* br    = (const float*)d_in[9];
    const float* wout  = (const float*)d_in[10];
    const float* bout  = (const float*)d_in[11];
    float* out = (float*)d_out;

    unsigned short* leftT  = (unsigned short*)d_ws;
    unsigned short* rightT = leftT + 256 * 32 * 128;
    unsigned short* w3     = rightT + 256 * 32 * 128;
    unsigned short* wTg    = w3 + 131072;

    k_prep<<<dim3(72), 256, 0, stream>>>(wout, wl, wr, w3, wTg);
    k_lnproj<<<dim3(256, 4), 256, 0, stream>>>(msa, gamma, beta, wTg, bl, br, leftT, rightT);
    k_outer<<<dim3(32, 64), 512, 0, stream>>>(leftT, rightT, w3, bout, pairI, out);
}

// Round 5
// 180.117 us; speedup vs baseline: 1.1634x; 1.0554x over previous
//
#include <hip/hip_runtime.h>

// Shapes: msa [1,128,256,256] f32, pair [1,256,256,128] f32, out same as pair.
// ws: leftT [256 l][4 kk][2 iLow][64 lane][8] bf16  (MFMA A-fragment-direct)
//     rightT same | w3 [16 ck][2 inner][2 tt][4 w][64 lane][8 e] bf16
//     | wTg [64 c][256 d] bf16

typedef float v4f __attribute__((ext_vector_type(4)));
typedef short v8s __attribute__((ext_vector_type(8)));

static __device__ inline unsigned short f2bf(float x) {
    unsigned int u = __builtin_bit_cast(unsigned int, x);
    return (unsigned short)((u + 0x7fffu + ((u >> 16) & 1u)) >> 16);
}

// global->LDS direct copy, 16 B per lane (wave-uniform LDS base + lane*16)
static __device__ inline void gl_lds16(const unsigned short* g, unsigned short* l) {
    __builtin_amdgcn_global_load_lds(
        (const __attribute__((address_space(1))) unsigned int*)g,
        (__attribute__((address_space(3))) unsigned int*)(unsigned long long)l,
        16, 0, 0);
}

// ---------------- one-time weight reformat ----------------
// blocks 0..63: w3 (fragment-direct, p = w*32+tt*16+l15); blocks 64..71: wTg [c][d]
__global__ __launch_bounds__(256) void k_prep(const float* __restrict__ w_out,
                                              const float* __restrict__ wl,
                                              const float* __restrict__ wr,
                                              unsigned short* __restrict__ w3,
                                              unsigned short* __restrict__ wTg) {
    const int b = blockIdx.x, t = threadIdx.x;
    unsigned short tmp[8];
    if (b < 64) {
        int tgt = b * 2048 + t * 8;            // linear in w3
        int lane6 = (tgt >> 3) & 63, quad = lane6 >> 4, l15 = lane6 & 15;
        int w = (tgt >> 9) & 3, tt = (tgt >> 11) & 1;
        int inner = (tgt >> 12) & 1, ck = tgt >> 13;
        int p = w * 32 + tt * 16 + l15;
        for (int e = 0; e < 8; ++e) {
            int kp = ck * 64 + inner * 32 + quad * 8 + e;   // k' this lane-element feeds
            int j1 = (kp >> 9) & 1, qd = (kp >> 7) & 3, lp = (kp >> 3) & 15;
            int i1 = (kp >> 2) & 1, r = kp & 3;
            int ii = i1 * 16 + qd * 4 + r, jj = j1 * 16 + lp;
            tmp[e] = f2bf(w_out[(ii * 32 + jj) * 128 + p]);
        }
        *(uint4*)&w3[tgt] = *(const uint4*)tmp;
    } else {
        int tgt = (b - 64) * 2048 + t * 8;     // linear = c*256 + d
        int c = tgt >> 8, d0 = tgt & 255;
        const float* src = (c < 32) ? wl : wr;
        int cc = c & 31;
        for (int e = 0; e < 8; ++e) tmp[e] = f2bf(src[(d0 + e) * 32 + cc]);
        *(uint4*)&wTg[tgt] = *(const uint4*)tmp;
    }
}

// ---------------- LayerNorm + left/right projection ----------------
// grid (256 l, 4 s-quarters), block 256.
__global__ __launch_bounds__(256) void k_lnproj(
    const float* __restrict__ msa, const float* __restrict__ gamma, const float* __restrict__ beta,
    const unsigned short* __restrict__ wTg, const float* __restrict__ bl, const float* __restrict__ br,
    unsigned short* __restrict__ leftT, unsigned short* __restrict__ rightT) {
    __shared__ unsigned short xb[32 * 264];     // [32 s][256 d + 8 pad]
    __shared__ unsigned short wlds[64 * 264];   // [64 c][256 d + 8 pad]
    __shared__ unsigned short outT[64 * 40];    // [64 c][32 s + 8 pad]

    const int t = threadIdx.x, lane = t & 63, w = t >> 6;
    const int l = blockIdx.x, s0 = blockIdx.y * 32;
    const int quad = lane >> 4, l15 = lane & 15;

    // stage W: coalesced b128, padded rows (min-conflict writes)
    for (int it = 0; it < 8; ++it) {
        int idx = it * 2048 + t * 8;
        *(uint4*)&wlds[(idx >> 8) * 264 + (idx & 255)] = *(const uint4*)&wTg[idx];
    }

    // LayerNorm: wave does 8 rows, reduction batched for 8-way ILP
    float4 g4 = *(const float4*)&gamma[lane * 4];
    float4 be4 = *(const float4*)&beta[lane * 4];
    float4 vr[8]; float s1[8], s2[8];
    for (int r = 0; r < 8; ++r) {
        const float* row = msa + (size_t)((s0 + w * 8 + r) * 256 + l) * 256;
        vr[r] = *(const float4*)&row[lane * 4];
    }
    for (int r = 0; r < 8; ++r) {
        float4 v = vr[r];
        s1[r] = v.x + v.y + v.z + v.w;
        s2[r] = v.x * v.x + v.y * v.y + v.z * v.z + v.w * v.w;
    }
    for (int o = 32; o > 0; o >>= 1)
        for (int r = 0; r < 8; ++r) { s1[r] += __shfl_xor(s1[r], o); s2[r] += __shfl_xor(s2[r], o); }
    for (int r = 0; r < 8; ++r) {
        float mu = s1[r] * (1.f / 256);
        float rs = rsqrtf(s2[r] * (1.f / 256) - mu * mu + 1e-5f);
        float4 v = vr[r];
        ushort4 xs;
        xs.x = f2bf((v.x - mu) * rs * g4.x + be4.x);
        xs.y = f2bf((v.y - mu) * rs * g4.y + be4.y);
        xs.z = f2bf((v.z - mu) * rs * g4.z + be4.z);
        xs.w = f2bf((v.w - mu) * rs * g4.w + be4.w);
        *(ushort4*)&xb[(w * 8 + r) * 264 + lane * 4] = xs;
    }
    __syncthreads();

    // MFMA: M=32 (s), N=64 (c), K=256
    const int mt = w >> 1, ntb = (w & 1) * 2;
    v4f acc[2] = {};
    const int frow = (mt * 16 + l15) * 264;
    for (int ks = 0; ks < 8; ++ks) {
        int k = ks * 32 + quad * 8;
        v8s a = *(const v8s*)&xb[frow + k];
        v8s b0 = *(const v8s*)&wlds[(ntb * 16 + l15) * 264 + k];
        v8s b1 = *(const v8s*)&wlds[((ntb + 1) * 16 + l15) * 264 + k];
        acc[0] = __builtin_amdgcn_mfma_f32_16x16x32_bf16(a, b0, acc[0], 0, 0, 0);
        acc[1] = __builtin_amdgcn_mfma_f32_16x16x32_bf16(a, b1, acc[1], 0, 0, 0);
    }

    for (int tn = 0; tn < 2; ++tn) {
        int c = (ntb + tn) * 16 + l15;
        float bias = c < 32 ? bl[c] : br[c - 32];
        float scale = c < 32 ? 1.f : (1.f / 128);
        for (int r = 0; r < 4; ++r)
            outT[c * 40 + mt * 16 + quad * 4 + r] = f2bf((acc[tn][r] + bias) * scale);
    }
    __syncthreads();

    // fragment-direct global writes: element (c, s = by*32 + sl) ->
    //   T[l*4096 + by*1024 + (c>>4)*512 + (sl>>3)*128 + (c&15)*8 + (sl&7)]
    {
        int c = t >> 2, q = t & 3;               // q = sl chunk (8 s each)
        uint4 vv = *(const uint4*)&outT[c * 40 + q * 8];
        int cc = c & 31;
        unsigned short* base = (c < 32) ? leftT : rightT;
        unsigned short* dst = base + l * 4096 + blockIdx.y * 1024
                            + (cc >> 4) * 512 + q * 128 + (cc & 15) * 8;
        *(uint4*)dst = vv;
    }
}

// ---------------- fused outer-product + w_out projection ----------------
// grid (64,64): 4x4 (l,m) tile, 256 threads (4 waves, 2x2). LDS 32 KB.
// Phase A staged via global_load_lds (fragment-direct layout -> linear copy,
// conflict-free b128 reads). Phase B: w3 fragment-direct from L2, split acc chains.
__global__ __launch_bounds__(256, 4) void k_outer(
    const unsigned short* __restrict__ leftT, const unsigned short* __restrict__ rightT,
    const unsigned short* __restrict__ w2g, const float* __restrict__ bout,
    const float* __restrict__ pairIn, float* __restrict__ out) {
    __shared__ alignas(16) unsigned short smem[16384];   // 32 KB
    unsigned short* Ah = smem;            // [4 l][2 kl][2 io][64 lane][8] (one kh half)
    unsigned short* Bh = smem + 8192;
    unsigned short* Obuf = smem;          // [16 px][1024 k'] alias, XOR-swizzled

    const int t = threadIdx.x, lane = t & 63, w = t >> 6;
    const int l0 = blockIdx.x * 4, m0 = blockIdx.y * 4;
    const int wm = w & 1, wn = w >> 1;
    const int quad = lane >> 4, l15 = lane & 15;

    // ---- pairIn prefetch (hides epilogue HBM latency)
    float pf[8];
#pragma unroll
    for (int tt = 0; tt < 2; ++tt)
#pragma unroll
        for (int r = 0; r < 4; ++r) {
            int pr = quad * 4 + r;
            int p = (w * 2 + tt) * 16 + l15;
            size_t idx = (size_t)((l0 + (pr >> 2)) * 256 + (m0 + (pr & 3))) * 128 + p;
            pf[tt * 4 + r] = pairIn[idx];
        }

    const unsigned short* Asrc = leftT + l0 * 4096;
    const unsigned short* Bsrc = rightT + m0 * 4096;

    // ---- phase A: staged halves (kh), fragment-direct layout in LDS
    v4f acc[4][4] = {};
    for (int kh = 0; kh < 2; ++kh) {
        if (kh) __syncthreads();          // kh=0 LDS reads done before overwrite
#pragma unroll
        for (int it = 0; it < 4; ++it) {
            int x = (it * 256 + t) * 8;   // shorts; lane-contiguous 16B chunks
            gl_lds16(&Asrc[(x >> 11) * 4096 + kh * 2048 + (x & 2047)], &Ah[x]);
            gl_lds16(&Bsrc[(x >> 11) * 4096 + kh * 2048 + (x & 2047)], &Bh[x]);
        }
        __syncthreads();                  // drains global_load_lds (vmcnt) + barrier
#pragma unroll
        for (int kl = 0; kl < 2; ++kl) {
            v8s a[4], bb[4];
#pragma unroll
            for (int i = 0; i < 4; ++i)
                a[i] = *(const v8s*)&Ah[(wm * 2 + (i >> 1)) * 2048 + kl * 1024 + (i & 1) * 512 + lane * 8];
#pragma unroll
            for (int j = 0; j < 4; ++j)
                bb[j] = *(const v8s*)&Bh[(wn * 2 + (j >> 1)) * 2048 + kl * 1024 + (j & 1) * 512 + lane * 8];
#pragma unroll
            for (int i = 0; i < 4; ++i)
#pragma unroll
                for (int j = 0; j < 4; ++j)
                    acc[i][j] = __builtin_amdgcn_mfma_f32_16x16x32_bf16(a[i], bb[j], acc[i][j], 0, 0, 0);
        }
    }
    __syncthreads();   // phase-A LDS reads done before Obuf overwrite

    // ---- w3 initial fragments: issue now, latency hides under scatter VALU
    const unsigned short* wsrc = w2g + w * 512 + lane * 8;
    v8s f0 = *(const v8s*)&wsrc[0];        // (ck=0, inner0, tt0)
    v8s f1 = *(const v8s*)&wsrc[2048];     // (0, inner0, tt1)
    v8s f2 = *(const v8s*)&wsrc[4096];     // (0, inner1, tt0)
    v8s f3 = *(const v8s*)&wsrc[6144];     // (0, inner1, tt1)

    // ---- scatter acc -> Obuf, k' = j1*512+quad*128+l15*8+i1*4+r
    for (int a2 = 0; a2 < 2; ++a2)
        for (int b2 = 0; b2 < 2; ++b2) {
            int P = (wm * 2 + a2) * 4 + wn * 2 + b2;
            for (int j1 = 0; j1 < 2; ++j1) {
                unsigned short tmp8[8];
                for (int i1 = 0; i1 < 2; ++i1)
                    for (int r = 0; r < 4; ++r)
                        tmp8[i1 * 4 + r] = f2bf(acc[a2 * 2 + i1][b2 * 2 + j1][r]);
                int pg = (j1 * 64 + lane) ^ (P & 7) ^ ((P & 8) << 3);
                *(uint4*)&Obuf[P * 1024 + pg * 8] = *(const uint4*)tmp8;
            }
        }
    __syncthreads();

    // ---- phase B: P[16][128] = Obuf @ W2, split acc chains (inner0/inner1)
    v4f aI0[2] = {}, aI1[2] = {};
#pragma unroll
    for (int ck = 0; ck < 16; ++ck) {
        v8s c0 = f0, c1 = f1, c2 = f2, c3 = f3;
        if (ck < 15) {
            const unsigned short* nx = wsrc + (ck + 1) * 8192;
            f0 = *(const v8s*)&nx[0];
            f1 = *(const v8s*)&nx[2048];
            f2 = *(const v8s*)&nx[4096];
            f3 = *(const v8s*)&nx[6144];
        }
        {
            int g = ck * 8 + quad;
            v8s a = *(const v8s*)&Obuf[l15 * 1024 + ((g ^ (l15 & 7) ^ ((l15 & 8) << 3)) << 3)];
            aI0[0] = __builtin_amdgcn_mfma_f32_16x16x32_bf16(a, c0, aI0[0], 0, 0, 0);
            aI0[1] = __builtin_amdgcn_mfma_f32_16x16x32_bf16(a, c1, aI0[1], 0, 0, 0);
        }
        {
            int g = ck * 8 + 4 + quad;
            v8s a = *(const v8s*)&Obuf[l15 * 1024 + ((g ^ (l15 & 7) ^ ((l15 & 8) << 3)) << 3)];
            aI1[0] = __builtin_amdgcn_mfma_f32_16x16x32_bf16(a, c2, aI1[0], 0, 0, 0);
            aI1[1] = __builtin_amdgcn_mfma_f32_16x16x32_bf16(a, c3, aI1[1], 0, 0, 0);
        }
    }

    // ---- epilogue: out = pair + P + b_out (64B-line-exact scatter, proven clean)
#pragma unroll
    for (int tt = 0; tt < 2; ++tt) {
        int p = (w * 2 + tt) * 16 + l15;
        float bo = bout[p];
        v4f acc2 = aI0[tt] + aI1[tt];
#pragma unroll
        for (int r = 0; r < 4; ++r) {
            int pr = quad * 4 + r;
            size_t idx = (size_t)((l0 + (pr >> 2)) * 256 + (m0 + (pr & 3))) * 128 + p;
            out[idx] = pf[tt * 4 + r] + bo + acc2[r];
        }
    }
}

extern "C" void kernel_launch(void* const* d_in, const int* in_sizes, int n_in,
                              void* d_out, int out_size, void* d_ws, size_t ws_size,
                              hipStream_t stream) {
    const float* msa   = (const float*)d_in[0];
    const float* pairI = (const float*)d_in[1];
    const float* gamma = (const float*)d_in[4];
    const float* beta  = (const float*)d_in[5];
    const float* wl    = (const float*)d_in[6];
    const float* bl    = (const float*)d_in[7];
    const float* wr    = (const float*)d_in[8];
    const float* br    = (const float*)d_in[9];
    const float* wout  = (const float*)d_in[10];
    const float* bout  = (const float*)d_in[11];
    float* out = (float*)d_out;

    unsigned short* leftT  = (unsigned short*)d_ws;
    unsigned short* rightT = leftT + 256 * 32 * 128;
    unsigned short* w3     = rightT + 256 * 32 * 128;
    unsigned short* wTg    = w3 + 131072;

    k_prep<<<dim3(72), 256, 0, stream>>>(wout, wl, wr, w3, wTg);
    k_lnproj<<<dim3(256, 4), 256, 0, stream>>>(msa, gamma, beta, wTg, bl, br, leftT, rightT);
    k_outer<<<dim3(64, 64), 256, 0, stream>>>(leftT, rightT, w3, bout, pairI, out);
}

// Round 6
// 172.182 us; speedup vs baseline: 1.2170x; 1.0461x over previous
//
#include <hip/hip_runtime.h>

// Shapes: msa [1,128,256,256] f32, pair [1,256,256,128] f32, out same as pair.
// ws: leftT [256 l][4 kk][2 iLow][64 lane][8] bf16  (MFMA A-fragment-direct)
//     rightT same | w3 [16 ck][2 inner][2 tt][4 w][64 lane][8 e] bf16
//     | wB [32 frag: nt*8+ks][64 lane][8 e] bf16 (k_lnproj B-fragment-direct)

typedef float v4f __attribute__((ext_vector_type(4)));
typedef short v8s __attribute__((ext_vector_type(8)));

static __device__ inline unsigned short f2bf(float x) {
    unsigned int u = __builtin_bit_cast(unsigned int, x);
    return (unsigned short)((u + 0x7fffu + ((u >> 16) & 1u)) >> 16);
}

// global->LDS direct copy, 16 B per lane (wave-uniform LDS base + lane*16)
static __device__ inline void gl_lds16(const unsigned short* g, unsigned short* l) {
    __builtin_amdgcn_global_load_lds(
        (const __attribute__((address_space(1))) unsigned int*)g,
        (__attribute__((address_space(3))) unsigned int*)(unsigned long long)l,
        16, 0, 0);
}

// ---------------- one-time weight reformat ----------------
// blocks 0..63: w3 (fragment-direct, p = w*32+tt*16+l15)
// blocks 64..71: wB (k_lnproj B-fragments: frag = nt*8+ks, c = nt*16+l15, d = ks*32+quad*8+e)
__global__ __launch_bounds__(256) void k_prep(const float* __restrict__ w_out,
                                              const float* __restrict__ wl,
                                              const float* __restrict__ wr,
                                              unsigned short* __restrict__ w3,
                                              unsigned short* __restrict__ wB) {
    const int b = blockIdx.x, t = threadIdx.x;
    unsigned short tmp[8];
    if (b < 64) {
        int tgt = b * 2048 + t * 8;            // linear in w3
        int lane6 = (tgt >> 3) & 63, quad = lane6 >> 4, l15 = lane6 & 15;
        int w = (tgt >> 9) & 3, tt = (tgt >> 11) & 1;
        int inner = (tgt >> 12) & 1, ck = tgt >> 13;
        int p = w * 32 + tt * 16 + l15;
        for (int e = 0; e < 8; ++e) {
            int kp = ck * 64 + inner * 32 + quad * 8 + e;   // k' this lane-element feeds
            int j1 = (kp >> 9) & 1, qd = (kp >> 7) & 3, lp = (kp >> 3) & 15;
            int i1 = (kp >> 2) & 1, r = kp & 3;
            int ii = i1 * 16 + qd * 4 + r, jj = j1 * 16 + lp;
            tmp[e] = f2bf(w_out[(ii * 32 + jj) * 128 + p]);
        }
        *(uint4*)&w3[tgt] = *(const uint4*)tmp;
    } else {
        int tgt = (b - 64) * 2048 + t * 8;     // linear in wB (32 frag x 512)
        int frag = tgt >> 9, lane6 = (tgt >> 3) & 63;
        int nt = frag >> 3, ks = frag & 7;
        int quad = lane6 >> 4, l15 = lane6 & 15;
        int c = nt * 16 + l15;
        const float* src = (c < 32) ? wl : wr;
        int cc = c & 31;
        for (int e = 0; e < 8; ++e) {
            int d = ks * 32 + quad * 8 + e;
            tmp[e] = f2bf(src[d * 32 + cc]);
        }
        *(uint4*)&wB[tgt] = *(const uint4*)tmp;
    }
}

// ---------------- LayerNorm + left/right projection ----------------
// grid (256 l, 4 s-quarters), block 256. B-fragments direct from L2 (no wlds).
__global__ __launch_bounds__(256) void k_lnproj(
    const float* __restrict__ msa, const float* __restrict__ gamma, const float* __restrict__ beta,
    const unsigned short* __restrict__ wB, const float* __restrict__ bl, const float* __restrict__ br,
    unsigned short* __restrict__ leftT, unsigned short* __restrict__ rightT) {
    __shared__ unsigned short xb[32 * 264];     // [32 s][256 d + 8 pad]
    __shared__ unsigned short outT[64 * 40];    // [64 c][32 s + 8 pad]

    const int t = threadIdx.x, lane = t & 63, w = t >> 6;
    const int l = blockIdx.x, s0 = blockIdx.y * 32;
    const int quad = lane >> 4, l15 = lane & 15;

    // LayerNorm: wave does 8 rows, reduction batched for 8-way ILP
    float4 g4 = *(const float4*)&gamma[lane * 4];
    float4 be4 = *(const float4*)&beta[lane * 4];
    float4 vr[8]; float s1[8], s2[8];
    for (int r = 0; r < 8; ++r) {
        const float* row = msa + (size_t)((s0 + w * 8 + r) * 256 + l) * 256;
        vr[r] = *(const float4*)&row[lane * 4];
    }
    for (int r = 0; r < 8; ++r) {
        float4 v = vr[r];
        s1[r] = v.x + v.y + v.z + v.w;
        s2[r] = v.x * v.x + v.y * v.y + v.z * v.z + v.w * v.w;
    }
    for (int o = 32; o > 0; o >>= 1)
        for (int r = 0; r < 8; ++r) { s1[r] += __shfl_xor(s1[r], o); s2[r] += __shfl_xor(s2[r], o); }
    for (int r = 0; r < 8; ++r) {
        float mu = s1[r] * (1.f / 256);
        float rs = rsqrtf(s2[r] * (1.f / 256) - mu * mu + 1e-5f);
        float4 v = vr[r];
        ushort4 xs;
        xs.x = f2bf((v.x - mu) * rs * g4.x + be4.x);
        xs.y = f2bf((v.y - mu) * rs * g4.y + be4.y);
        xs.z = f2bf((v.z - mu) * rs * g4.z + be4.z);
        xs.w = f2bf((v.w - mu) * rs * g4.w + be4.w);
        *(ushort4*)&xb[(w * 8 + r) * 264 + lane * 4] = xs;
    }
    __syncthreads();

    // MFMA: M=32 (s), N=64 (c), K=256 — B straight from L2 (frag-direct wB)
    const int mt = w >> 1, ntb = (w & 1) * 2;
    v4f acc[2] = {};
    const int frow = (mt * 16 + l15) * 264;
    const unsigned short* wBp = wB + lane * 8;
#pragma unroll
    for (int ks = 0; ks < 8; ++ks) {
        v8s a = *(const v8s*)&xb[frow + ks * 32 + quad * 8];
        v8s b0 = *(const v8s*)&wBp[(ntb * 8 + ks) * 512];
        v8s b1 = *(const v8s*)&wBp[((ntb + 1) * 8 + ks) * 512];
        acc[0] = __builtin_amdgcn_mfma_f32_16x16x32_bf16(a, b0, acc[0], 0, 0, 0);
        acc[1] = __builtin_amdgcn_mfma_f32_16x16x32_bf16(a, b1, acc[1], 0, 0, 0);
    }

    for (int tn = 0; tn < 2; ++tn) {
        int c = (ntb + tn) * 16 + l15;
        float bias = c < 32 ? bl[c] : br[c - 32];
        float scale = c < 32 ? 1.f : (1.f / 128);
        for (int r = 0; r < 4; ++r)
            outT[c * 40 + mt * 16 + quad * 4 + r] = f2bf((acc[tn][r] + bias) * scale);
    }
    __syncthreads();

    // fragment-direct global writes: element (c, s = by*32 + sl) ->
    //   T[l*4096 + by*1024 + (c>>4)*512 + (sl>>3)*128 + (c&15)*8 + (sl&7)]
    {
        int c = t >> 2, q = t & 3;               // q = sl chunk (8 s each)
        uint4 vv = *(const uint4*)&outT[c * 40 + q * 8];
        int cc = c & 31;
        unsigned short* base = (c < 32) ? leftT : rightT;
        unsigned short* dst = base + l * 4096 + blockIdx.y * 1024
                            + (cc >> 4) * 512 + q * 128 + (cc & 15) * 8;
        *(uint4*)dst = vv;
    }
}

// ---------------- fused outer-product + w_out projection ----------------
// grid (64,64): 4x4 (l,m) tile, 256 threads (4 waves, 2x2). LDS 32 KB.
// Phase A staged via global_load_lds. Phase B: 2-deep rolling w3 prefetch
// (reload-after-use, no copies), launch_bounds(256,3) for register headroom.
__global__ __launch_bounds__(256, 3) void k_outer(
    const unsigned short* __restrict__ leftT, const unsigned short* __restrict__ rightT,
    const unsigned short* __restrict__ w2g, const float* __restrict__ bout,
    const float* __restrict__ pairIn, float* __restrict__ out) {
    __shared__ alignas(16) unsigned short smem[16384];   // 32 KB
    unsigned short* Ah = smem;            // [4 l][2 kl][2 io][64 lane][8] (one kh half)
    unsigned short* Bh = smem + 8192;
    unsigned short* Obuf = smem;          // [16 px][1024 k'] alias, XOR-swizzled

    const int t = threadIdx.x, lane = t & 63, w = t >> 6;
    const int l0 = blockIdx.x * 4, m0 = blockIdx.y * 4;
    const int wm = w & 1, wn = w >> 1;
    const int quad = lane >> 4, l15 = lane & 15;

    // ---- pairIn prefetch (hides epilogue HBM latency)
    float pf[8];
#pragma unroll
    for (int tt = 0; tt < 2; ++tt)
#pragma unroll
        for (int r = 0; r < 4; ++r) {
            int pr = quad * 4 + r;
            int p = (w * 2 + tt) * 16 + l15;
            size_t idx = (size_t)((l0 + (pr >> 2)) * 256 + (m0 + (pr & 3))) * 128 + p;
            pf[tt * 4 + r] = pairIn[idx];
        }

    const unsigned short* Asrc = leftT + l0 * 4096;
    const unsigned short* Bsrc = rightT + m0 * 4096;

    // ---- phase A: staged halves (kh), fragment-direct layout in LDS
    v4f acc[4][4] = {};
    for (int kh = 0; kh < 2; ++kh) {
        if (kh) __syncthreads();          // kh=0 LDS reads done before overwrite
#pragma unroll
        for (int it = 0; it < 4; ++it) {
            int x = (it * 256 + t) * 8;   // shorts; lane-contiguous 16B chunks
            gl_lds16(&Asrc[(x >> 11) * 4096 + kh * 2048 + (x & 2047)], &Ah[x]);
            gl_lds16(&Bsrc[(x >> 11) * 4096 + kh * 2048 + (x & 2047)], &Bh[x]);
        }
        __syncthreads();                  // drains global_load_lds (vmcnt) + barrier
#pragma unroll
        for (int kl = 0; kl < 2; ++kl) {
            v8s a[4], bb[4];
#pragma unroll
            for (int i = 0; i < 4; ++i)
                a[i] = *(const v8s*)&Ah[(wm * 2 + (i >> 1)) * 2048 + kl * 1024 + (i & 1) * 512 + lane * 8];
#pragma unroll
            for (int j = 0; j < 4; ++j)
                bb[j] = *(const v8s*)&Bh[(wn * 2 + (j >> 1)) * 2048 + kl * 1024 + (j & 1) * 512 + lane * 8];
#pragma unroll
            for (int i = 0; i < 4; ++i)
#pragma unroll
                for (int j = 0; j < 4; ++j)
                    acc[i][j] = __builtin_amdgcn_mfma_f32_16x16x32_bf16(a[i], bb[j], acc[i][j], 0, 0, 0);
        }
    }
    __syncthreads();   // phase-A LDS reads done before Obuf overwrite

    // ---- w3 fragments for ck=0 and ck=1: issue now, latency hides under scatter
    const unsigned short* wsrc = w2g + w * 512 + lane * 8;
    v8s A0 = *(const v8s*)&wsrc[0];        // (ck=0, inner0, tt0)
    v8s A1 = *(const v8s*)&wsrc[2048];     // (0, inner0, tt1)
    v8s A2 = *(const v8s*)&wsrc[4096];     // (0, inner1, tt0)
    v8s A3 = *(const v8s*)&wsrc[6144];     // (0, inner1, tt1)
    v8s B0 = *(const v8s*)&wsrc[8192];     // (ck=1, ...)
    v8s B1 = *(const v8s*)&wsrc[8192 + 2048];
    v8s B2 = *(const v8s*)&wsrc[8192 + 4096];
    v8s B3 = *(const v8s*)&wsrc[8192 + 6144];

    // ---- scatter acc -> Obuf, k' = j1*512+quad*128+l15*8+i1*4+r
    for (int a2 = 0; a2 < 2; ++a2)
        for (int b2 = 0; b2 < 2; ++b2) {
            int P = (wm * 2 + a2) * 4 + wn * 2 + b2;
            for (int j1 = 0; j1 < 2; ++j1) {
                unsigned short tmp8[8];
                for (int i1 = 0; i1 < 2; ++i1)
                    for (int r = 0; r < 4; ++r)
                        tmp8[i1 * 4 + r] = f2bf(acc[a2 * 2 + i1][b2 * 2 + j1][r]);
                int pg = (j1 * 64 + lane) ^ (P & 7) ^ ((P & 8) << 3);
                *(uint4*)&Obuf[P * 1024 + pg * 8] = *(const uint4*)tmp8;
            }
        }
    __syncthreads();

    // ---- phase B: P[16][128] = Obuf @ W2, 2-deep rolling prefetch,
    //      split acc chains (inner0/inner1), reload-after-use (no copies)
    v4f aI0[2] = {}, aI1[2] = {};
#pragma unroll
    for (int ck = 0; ck < 16; ck += 2) {
        {   // ---- even ck: A-set
            int g = ck * 8 + quad;
            v8s a = *(const v8s*)&Obuf[l15 * 1024 + ((g ^ (l15 & 7) ^ ((l15 & 8) << 3)) << 3)];
            aI0[0] = __builtin_amdgcn_mfma_f32_16x16x32_bf16(a, A0, aI0[0], 0, 0, 0);
            aI0[1] = __builtin_amdgcn_mfma_f32_16x16x32_bf16(a, A1, aI0[1], 0, 0, 0);
            int g2 = ck * 8 + 4 + quad;
            v8s a2 = *(const v8s*)&Obuf[l15 * 1024 + ((g2 ^ (l15 & 7) ^ ((l15 & 8) << 3)) << 3)];
            aI1[0] = __builtin_amdgcn_mfma_f32_16x16x32_bf16(a2, A2, aI1[0], 0, 0, 0);
            aI1[1] = __builtin_amdgcn_mfma_f32_16x16x32_bf16(a2, A3, aI1[1], 0, 0, 0);
            if (ck + 2 < 16) {
                const unsigned short* nx = wsrc + (ck + 2) * 8192;
                A0 = *(const v8s*)&nx[0];
                A1 = *(const v8s*)&nx[2048];
                A2 = *(const v8s*)&nx[4096];
                A3 = *(const v8s*)&nx[6144];
            }
        }
        {   // ---- odd ck+1: B-set
            int g = (ck + 1) * 8 + quad;
            v8s a = *(const v8s*)&Obuf[l15 * 1024 + ((g ^ (l15 & 7) ^ ((l15 & 8) << 3)) << 3)];
            aI0[0] = __builtin_amdgcn_mfma_f32_16x16x32_bf16(a, B0, aI0[0], 0, 0, 0);
            aI0[1] = __builtin_amdgcn_mfma_f32_16x16x32_bf16(a, B1, aI0[1], 0, 0, 0);
            int g2 = (ck + 1) * 8 + 4 + quad;
            v8s a2 = *(const v8s*)&Obuf[l15 * 1024 + ((g2 ^ (l15 & 7) ^ ((l15 & 8) << 3)) << 3)];
            aI1[0] = __builtin_amdgcn_mfma_f32_16x16x32_bf16(a2, B2, aI1[0], 0, 0, 0);
            aI1[1] = __builtin_amdgcn_mfma_f32_16x16x32_bf16(a2, B3, aI1[1], 0, 0, 0);
            if (ck + 3 < 16) {
                const unsigned short* nx = wsrc + (ck + 3) * 8192;
                B0 = *(const v8s*)&nx[0];
                B1 = *(const v8s*)&nx[2048];
                B2 = *(const v8s*)&nx[4096];
                B3 = *(const v8s*)&nx[6144];
            }
        }
    }

    // ---- epilogue: out = pair + P + b_out (64B-line-exact scatter, proven clean)
#pragma unroll
    for (int tt = 0; tt < 2; ++tt) {
        int p = (w * 2 + tt) * 16 + l15;
        float bo = bout[p];
        v4f acc2 = aI0[tt] + aI1[tt];
#pragma unroll
        for (int r = 0; r < 4; ++r) {
            int pr = quad * 4 + r;
            size_t idx = (size_t)((l0 + (pr >> 2)) * 256 + (m0 + (pr & 3))) * 128 + p;
            out[idx] = pf[tt * 4 + r] + bo + acc2[r];
        }
    }
}

extern "C" void kernel_launch(void* const* d_in, const int* in_sizes, int n_in,
                              void* d_out, int out_size, void* d_ws, size_t ws_size,
                              hipStream_t stream) {
    const float* msa   = (const float*)d_in[0];
    const float* pairI = (const float*)d_in[1];
    const float* gamma = (const float*)d_in[4];
    const float* beta  = (const float*)d_in[5];
    const float* wl    = (const float*)d_in[6];
    const float* bl    = (const float*)d_in[7];
    const float* wr    = (const float*)d_in[8];
    const float* br    = (const float*)d_in[9];
    const float* wout  = (const float*)d_in[10];
    const float* bout  = (const float*)d_in[11];
    float* out = (float*)d_out;

    unsigned short* leftT  = (unsigned short*)d_ws;
    unsigned short* rightT = leftT + 256 * 32 * 128;
    unsigned short* w3     = rightT + 256 * 32 * 128;
    unsigned short* wB     = w3 + 131072;

    k_prep<<<dim3(72), 256, 0, stream>>>(wout, wl, wr, w3, wB);
    k_lnproj<<<dim3(256, 4), 256, 0, stream>>>(msa, gamma, beta, wB, bl, br, leftT, rightT);
    k_outer<<<dim3(64, 64), 256, 0, stream>>>(leftT, rightT, w3, bout, pairI, out);
}